// Round 2
// baseline (264.758 us; speedup 1.0000x reference)
//
#include <hip/hip_runtime.h>

// Length_Regulate alignment matrix.
//   repeats = (int)(durations + 0.5)   [B, T], durations in [1,8) => repeats 1..8
//   ends = inclusive_cumsum(repeats); starts = ends - repeats
//   out[b, t, j] = 1.0f iff starts[j] <= t < ends[j]  (one-hot per (b,t) row)
//
// Round-1 post-mortem: hipMemset(268MB) + scatter cost ~89us attributed vs
// ~46us predicted -- two serialized graph nodes + scatter tail. This round:
// ONE streaming writer that emits final values directly at fill-kernel rate.
//   K1 (32 blocks): LDS scan + build inverse map inv[b][t] = one-hot column j
//                   (or -1 past the total). 512 KB in workspace, L2-resident.
//   K2 (4096 blocks): pure stream: per row read inv (wave-uniform, L1 hit),
//                   write 512 floats as coalesced float4. No LDS, no barrier,
//                   no search -- structurally the runtime fill kernel (6.5TB/s).

#define T_TEXT 512
#define RB 32                 // rows per writer block (64 KB tile)
#define WTHR 256              // writer block size

// ---- K1: scan + inverse map ----
__global__ __launch_bounds__(T_TEXT) void lr_scan_inv(
        const float* __restrict__ dur,
        int* __restrict__ inv,
        int max_len) {
    __shared__ int s[T_TEXT];
    const int b = blockIdx.x;
    const int tid = threadIdx.x;

    const int rep = (int)(dur[b * T_TEXT + tid] + 0.5f);  // same FP ops as ref
    s[tid] = rep;
    __syncthreads();
    for (int off = 1; off < T_TEXT; off <<= 1) {          // Hillis-Steele
        int v = s[tid];
        int add = (tid >= off) ? s[tid - off] : 0;
        __syncthreads();
        s[tid] = v + add;
        __syncthreads();
    }
    int end = s[tid];
    int start = end - rep;
    int total = s[T_TEXT - 1];
    if (end > max_len) end = max_len;

    int* invb = inv + b * max_len;
    for (int t = start; t < end; ++t) invb[t] = tid;      // <=8 stores/thread
    for (int t = total + tid; t < max_len; t += T_TEXT) invb[t] = -1;
}

// ---- K2: pure streaming writer ----
__global__ __launch_bounds__(WTHR) void lr_fill(
        const int* __restrict__ inv,
        float* __restrict__ out,
        int max_len) {
    const int b = blockIdx.y;
    const int t0 = blockIdx.x * RB;
    const int tid = threadIdx.x;

    const int* invb = inv + b * max_len + t0;
    float4* outv = (float4*)(out + ((size_t)b * max_len + t0) * T_TEXT);
    const int rows = (max_len - t0 < RB) ? (max_len - t0) : RB;
    const int nvec = rows * (T_TEXT / 4);

    #pragma unroll 4
    for (int f = tid; f < nvec; f += WTHR) {
        int r = f >> 7;               // row in tile (wave-uniform: 64 < 128)
        int c = (f & 127) << 2;       // starting column of this float4
        int j = invb[r];              // L1 broadcast hit
        float4 v = make_float4(0.f, 0.f, 0.f, 0.f);
        int d = j - c;
        if ((unsigned)d < 4u) ((float*)&v)[d] = 1.0f;
        outv[f] = v;
    }
}

// ---- fallback path (workspace too small): memset + scatter, round-1 code ----
__global__ __launch_bounds__(T_TEXT) void lr_scan_scatter(
        const float* __restrict__ dur,
        float* __restrict__ out,
        int max_len) {
    __shared__ int s[T_TEXT];
    const int b = blockIdx.x;
    const int tid = threadIdx.x;
    const int rep = (int)(dur[b * T_TEXT + tid] + 0.5f);
    s[tid] = rep;
    __syncthreads();
    for (int off = 1; off < T_TEXT; off <<= 1) {
        int v = s[tid];
        int add = (tid >= off) ? s[tid - off] : 0;
        __syncthreads();
        s[tid] = v + add;
        __syncthreads();
    }
    int end = s[tid];
    int start = end - rep;
    if (end > max_len) end = max_len;
    float* col = out + ((size_t)b * max_len) * T_TEXT + tid;
    for (int t = start; t < end; ++t) col[(size_t)t * T_TEXT] = 1.0f;
}

extern "C" void kernel_launch(void* const* d_in, const int* in_sizes, int n_in,
                              void* d_out, int out_size, void* d_ws, size_t ws_size,
                              hipStream_t stream) {
    const float* dur = (const float*)d_in[0];
    float* out = (float*)d_out;

    const int BT = in_sizes[0];           // B * T_TEXT elements (16384)
    const int B = BT / T_TEXT;            // 32
    const int max_len = out_size / BT;    // 4096

    const size_t inv_bytes = (size_t)B * max_len * sizeof(int);  // 512 KB

    if (ws_size >= inv_bytes) {
        int* inv = (int*)d_ws;
        lr_scan_inv<<<B, T_TEXT, 0, stream>>>(dur, inv, max_len);
        dim3 grid((max_len + RB - 1) / RB, B);
        lr_fill<<<grid, WTHR, 0, stream>>>(inv, out, max_len);
    } else {
        hipMemsetAsync(d_out, 0, (size_t)out_size * sizeof(float), stream);
        lr_scan_scatter<<<B, T_TEXT, 0, stream>>>(dur, out, max_len);
    }
}